// Round 7
// baseline (3871.262 us; speedup 1.0000x reference)
//
#include <hip/hip_runtime.h>
#include <stdint.h>

// Round 8: 4-CU FPS per batch (phase-1 issue /4) + R7 fused consumers.
//  - 32 fps blocks: batch b = blockIdx&7, sub k = blockIdx>>3 (blocks b,b+8,b+16,
//    b+24 land on one XCD under round-robin mapping -> L2-local slot exchange;
//    perf heuristic only, correctness placement-independent).
//  - Each fps block owns points [k*2048,(k+1)*2048): phase-1 = 2 pairs/thread.
//    Intra-block reduce = validated R6 path (DPP + ballot + LDS pairs + uniform
//    scan). Cross-block: block winner published as ONE u64 slot
//        (valbits<<32) | (s<<13) | global_idx
//    tag s embedded -> payload IS the polled word (no fence); parity-buffered
//    slots, skew<=1 proven (to overwrite tag-s, a block must have consumed all
//    s+1 slots). 4 disjoint plain atomic stores - NOT a contended atomicMax (R5
//    lesson). Ascending-k strict-> scan == lowest-index tie-break (exact).
//  - Consumers: 224 blocks, 56 slots/batch, 37 rounds; internals = validated R7.
//  - Residency: 96KB LDS/block -> 1 block/CU -> all 256 blocks resident.
//  - Workspace: fps_idx (64KB) ++ slots[8][2][4] u64 (512B), both poisoned 0xFF
//    (garbage tag 2047 can never false-match: slot parity 1 is rewritten at
//    s=1,3,... long before s=2047 polls it).

#define NBATCH 8
#define NPTS   8192
#define NCH    128
#define NGROUP 2048
#define NK     24
#define ROWLEN (2 * NCH + 3)   // 259

#define FPS_T    512
#define FPS_KS   4                        // fps blocks per batch
#define FPS_BLKS (NBATCH * FPS_KS)        // 32
#define BLK_PTS  (NPTS / FPS_KS)          // 2048 points per fps block
#define GBLOCKS  (256 - FPS_BLKS)         // 224 consumer blocks
#define GSLOTS   ((GBLOCKS / NBATCH) * 2) // 56 group slots per batch per round
#define GITERS   ((NGROUP + GSLOTS - 1) / GSLOTS)  // 37

typedef float v2f __attribute__((ext_vector_type(2)));
typedef unsigned long long u64;

struct __attribute__((packed, aligned(4))) f4s { float x, y, z, w; };  // dword-aligned 16B

__device__ __forceinline__ float sq3_nofma(float dx, float dy, float dz) {
#pragma clang fp contract(off)
  return dx * dx + dy * dy + dz * dz;
}

// numpy einsum contracted inner loop: acc = a0*b0; acc = fma(a1,b1,acc); acc = fma(a2,b2,acc)
__device__ __forceinline__ float dot3_fma(float ax, float ay, float az,
                                          float bx, float by, float bz) {
  float acc = __fmul_rn(ax, bx);
  acc = __fmaf_rn(ay, by, acc);
  acc = __fmaf_rn(az, bz, acc);
  return acc;
}

__device__ __forceinline__ float ballquery_sqr(float srcSq, float dstSq, float dot) {
#pragma clang fp contract(off)
  return (srcSq + dstSq) - 2.0f * dot;
}

template <int CTRL>
__device__ __forceinline__ float maxdpp(float v) {
  int s = __builtin_amdgcn_update_dpp(__builtin_bit_cast(int, v),
                                      __builtin_bit_cast(int, v),
                                      CTRL, 0xF, 0xF, false);
  return fmaxf(v, __builtin_bit_cast(float, s));
}

__device__ __forceinline__ float readlane_f(float v, int lane) {
  return __builtin_bit_cast(float,
      __builtin_amdgcn_readlane(__builtin_bit_cast(int, v), lane));
}

__global__ __launch_bounds__(FPS_T) void fused_kernel(const float* __restrict__ xyz,
                                                      const float* __restrict__ points,
                                                      int* __restrict__ fps_idx,
                                                      u64* __restrict__ slots,
                                                      float* __restrict__ out) {
  const int t = threadIdx.x;

  // Static LDS (~96.9 KB -> exactly 1 block/CU on every block).
  __shared__ float s_xyz[NPTS * 3];     // fps: centroid gather source
  union pair_t { struct { float v; int i; }; u64 u; };
  __shared__ __align__(16) pair_t s_p[2][8];
  __shared__ int s_aidx[2];             // group: per-half anchor index
  __shared__ int s_idx2[2][NK];         // group: per-half ball-query indices

  if (blockIdx.x < FPS_BLKS) {
    // ======================= FPS role (4 blocks per batch) =======================
    const int b = blockIdx.x & 7;       // batch == XCD (round-robin heuristic)
    const int k = blockIdx.x >> 3;      // sub-block 0..3, owns [k*2048,(k+1)*2048)
    const int lane = t & 63;
    const int w = t >> 6;               // 8 waves
    const float* xb = xyz + (size_t)b * NPTS * 3;
    u64* bslots = slots + (size_t)b * 2 * FPS_KS;   // [parity][k]

    {
      const float4* src4 = (const float4*)xb;
      float4* dst4 = (float4*)s_xyz;
      for (int i = t; i < (NPTS * 3) / 4; i += FPS_T) dst4[i] = src4[i];
    }

    // thread t owns CONTIGUOUS points [base, base+4): lane order == index order,
    // wave order == index order, block order == index order -> ballot+ctz and
    // ascending scans keep np.argmax first-index tie-break at every level.
    const int base = k * BLK_PTS + (t << 2);
    v2f px[2], py[2], pz[2], d2[2];
#pragma unroll
    for (int j = 0; j < 2; ++j) {
      const int n0 = base + 2 * j;
      px[j].x = xb[n0 * 3 + 0]; py[j].x = xb[n0 * 3 + 1]; pz[j].x = xb[n0 * 3 + 2];
      px[j].y = xb[n0 * 3 + 3]; py[j].y = xb[n0 * 3 + 4]; pz[j].y = xb[n0 * 3 + 5];
      d2[j].x = 1e10f; d2[j].y = 1e10f;
    }

    float cx = xb[0], cy = xb[1], cz = xb[2];   // centroid 0 = point 0
    if (k == 0 && t == 0)
      __hip_atomic_store(&fps_idx[b * NGROUP + 0], 0,
                         __ATOMIC_RELAXED, __HIP_MEMORY_SCOPE_AGENT);

    for (int s = 1; s < NGROUP; ++s) {
      const int p = s & 1;

      // ---- phase 1: packed min-update + value max (exact, contraction-free) ----
      float lv = -1.0f;
#pragma unroll
      for (int j = 0; j < 2; ++j) {
        v2f dx, dy, dz, dd, nd;
        {
#pragma clang fp contract(off)
          dx = px[j] - cx;                    // v_pk_add_f32 (neg)
          dy = py[j] - cy;
          dz = pz[j] - cz;
          dd = dx * dx + dy * dy + dz * dz;   // 3x pk_mul + 2x pk_add, never fused
        }
        nd.x = fminf(d2[j].x, dd.x);
        nd.y = fminf(d2[j].y, dd.y);
        d2[j] = nd;
        lv = fmaxf(fmaxf(nd.x, nd.y), lv);    // v_max3_f32
      }
      // first-index recovery: descending overwrite -> lowest matching index wins
      int kk = 0;
      if (d2[1].y == lv) kk = 3;
      if (d2[1].x == lv) kk = 2;
      if (d2[0].y == lv) kk = 1;
      if (d2[0].x == lv) kk = 0;
      const int li = base + kk;

      // ---- wave argmax via DPP (value max, then ballot for first index) ----
      float v = lv;
      v = maxdpp<0x111>(v);   // row_shr:1
      v = maxdpp<0x112>(v);   // row_shr:2
      v = maxdpp<0x114>(v);   // row_shr:4
      v = maxdpp<0x118>(v);   // row_shr:8
      v = maxdpp<0x142>(v);   // row_bcast15
      v = maxdpp<0x143>(v);   // row_bcast31
      const float wmax = readlane_f(v, 63);
      const u64 m = __ballot(lv == wmax);
      const int wl = (int)__builtin_ctzll(m);            // lowest lane = lowest index
      const int wli = __builtin_amdgcn_readlane(li, wl);
      if (lane == 0) {
        s_p[p][w].u = ((u64)(unsigned)wli << 32) |
                      (u64)__builtin_bit_cast(unsigned, wmax);
      }
      __syncthreads();   // orders s_p[p] write->read AND s_p[p^1] reuse

      // ---- phase 2: uniform scan of the 8 wave pairs -> block winner ----
      const float4* q = (const float4*)&s_p[p][0];
      const float4 q0 = q[0], q1 = q[1], q2 = q[2], q3 = q[3];
      float bv = q0.x;
      float biF = q0.y;   // index carried as raw bits; cndmask is bitwise-safe
      {
        const float vv[7] = { q0.z, q1.x, q1.z, q2.x, q2.z, q3.x, q3.z };
        const float ii[7] = { q0.w, q1.y, q1.w, q2.y, q2.w, q3.y, q3.w };
#pragma unroll
        for (int e = 0; e < 7; ++e) {
          const bool gt = vv[e] > bv;        // strict > : lowest wave wins ties
          bv  = gt ? vv[e] : bv;
          biF = gt ? ii[e] : biF;
        }
      }
      const int blk_i = __builtin_bit_cast(int, biF);

      // ---- publish block winner: self-contained u64 (tag s embedded) ----
      if (t == 0) {
        const u64 pk = ((u64)__builtin_bit_cast(unsigned, bv) << 32) |
                       ((u64)(unsigned)s << 13) | (u64)(unsigned)blk_i;
        __hip_atomic_store(&bslots[p * FPS_KS + k], pk,
                           __ATOMIC_RELAXED, __HIP_MEMORY_SCOPE_AGENT);
      }

      // ---- poll all 4 slots (uniform addr -> 1 txn/wave), scan ascending k ----
      float gv; int gi;
      {
        u64 sl[FPS_KS];
#pragma unroll
        for (int k2 = 0; k2 < FPS_KS; ++k2) {
          u64 vv2;
          while ((unsigned)(((vv2 = __hip_atomic_load(&bslots[p * FPS_KS + k2],
                                                      __ATOMIC_RELAXED,
                                                      __HIP_MEMORY_SCOPE_AGENT))
                             >> 13) & 0x7FF) != (unsigned)s)
            __builtin_amdgcn_s_sleep(1);
          sl[k2] = vv2;
        }
        gv = __builtin_bit_cast(float, (unsigned)(sl[0] >> 32));
        gi = (int)(sl[0] & 0x1FFF);
#pragma unroll
        for (int k2 = 1; k2 < FPS_KS; ++k2) {
          const float v2 = __builtin_bit_cast(float, (unsigned)(sl[k2] >> 32));
          const int i2 = (int)(sl[k2] & 0x1FFF);
          const bool gt = v2 > gv;           // strict > : lowest block wins ties
          gv = gt ? v2 : gv;
          gi = gt ? i2 : gi;
        }
      }

      if (k == 0 && t == 0)
        __hip_atomic_store(&fps_idx[b * NGROUP + s], gi,
                           __ATOMIC_RELAXED, __HIP_MEMORY_SCOPE_AGENT);

      // next centroid coords: broadcast LDS read
      const int b3 = gi * 3;
      cx = s_xyz[b3 + 0];
      cy = s_xyz[b3 + 1];
      cz = s_xyz[b3 + 2];
    }
    return;
  }

  // ======================= group role (persistent consumers) =======================
  const int gs = blockIdx.x - FPS_BLKS; // 0..223
  const int b = gs & 7;                 // batch (== XCD affinity, approx)
  const int sb = gs >> 3;               // 0..27
  const int h = t >> 8;                 // half (0/1)
  const int htid = t & 255;
  const float* xb = xyz + (size_t)b * NPTS * 3;
  const float* pb = points + (size_t)b * NPTS * NCH;
  const float R2 = (float)(0.2 * 0.2);

  for (int i = 0; i < GITERS; ++i) {
    const int g = i * GSLOTS + sb * 2 + h;
    const bool act = g < NGROUP;
    const int gb = (b << 11) | (g & 2047);

    // spin until fps produced this group's anchor index (payload == polled word)
    if (htid == 0 && act) {
      int v;
      while ((v = __hip_atomic_load(&fps_idx[gb], __ATOMIC_RELAXED,
                                    __HIP_MEMORY_SCOPE_AGENT)) == -1)
        __builtin_amdgcn_s_sleep(8);
      s_aidx[h] = v;
    }
    __syncthreads();

    int a_idx = 0;
    float cx = 0.f, cy = 0.f, cz = 0.f, srcSq = 0.f;
    if (act) {
      a_idx = s_aidx[h];
      cx = xb[a_idx * 3 + 0];
      cy = xb[a_idx * 3 + 1];
      cz = xb[a_idx * 3 + 2];
      srcSq = sq3_nofma(cx, cy, cz);

      if (htid < 64) {
        int cnt = 0;
        int first = 0;
        const u64 below = ((u64)1 << htid) - 1ull;
        for (int chunk = 0; chunk < NPTS / 128; ++chunk) {
          const int n0 = (chunk << 7) + (htid << 1);       // 2 points per lane
          const float* p = xb + (size_t)n0 * 3;            // 24B-aligned
          const float2 A = *(const float2*)(p + 0);        // x0 y0
          const float2 Bv = *(const float2*)(p + 2);       // z0 x1
          const float2 C = *(const float2*)(p + 4);        // y1 z1
          const float x0 = A.x, y0 = A.y, z0 = Bv.x;
          const float x1 = Bv.y, y1 = C.x, z1 = C.y;

          const float sqr0 = ballquery_sqr(srcSq, sq3_nofma(x0, y0, z0),
                                           dot3_fma(cx, cy, cz, x0, y0, z0));
          const float sqr1 = ballquery_sqr(srcSq, sq3_nofma(x1, y1, z1),
                                           dot3_fma(cx, cy, cz, x1, y1, z1));
          const bool ok0 = !(sqr0 > R2);
          const bool ok1 = !(sqr1 > R2);
          const u64 m0 = __ballot(ok0);
          const u64 m1 = __ballot(ok1);
          if (cnt == 0 && (m0 | m1)) {
            const int f0 = m0 ? (int)__builtin_ctzll(m0) : 64;
            const int f1 = m1 ? (int)__builtin_ctzll(m1) : 64;
            first = (f0 <= f1) ? ((chunk << 7) + 2 * f0) : ((chunk << 7) + 2 * f1 + 1);
          }
          const int p0 = cnt + (int)__popcll(m0 & below) + (int)__popcll(m1 & below);
          const int p1 = p0 + (ok0 ? 1 : 0);
          if (ok0 && p0 < NK) s_idx2[h][p0] = n0;
          if (ok1 && p1 < NK) s_idx2[h][p1] = n0 + 1;
          cnt += (int)__popcll(m0) + (int)__popcll(m1);
          if (cnt >= NK) break;
        }
        if (htid >= cnt && htid < NK) s_idx2[h][htid] = first;  // pad with first in-radius
      }
    }
    __syncthreads();

    if (act) {
      // output 0: new_xyz (exact copy of the centroid row)
      if (htid == 0) {
        float* onx = out + (size_t)gb * 3;
        onx[0] = cx; onx[1] = cy; onx[2] = cz;
      }

      // output 1: rows [points[idx](128) | xyz[idx](3) | points[anchor](128)]
      float* op = out + (size_t)NBATCH * NGROUP * 3 + (size_t)gb * (NK * ROWLEN);
      const float* anchor = pb + (size_t)a_idx * NCH;

      // points part: 24 rows x 32 float4
#pragma unroll
      for (int it = 0; it < 3; ++it) {
        const int vidx = htid + (it << 8);
        const int kx = vidx >> 5;
        const int c4 = vidx & 31;
        const int si = s_idx2[h][kx];
        const f4s val = *(const f4s*)(pb + (size_t)si * NCH + (c4 << 2));
        *(f4s*)(op + kx * ROWLEN + (c4 << 2)) = val;
      }
      // anchor part: 24 rows x 32 float4
#pragma unroll
      for (int it = 0; it < 3; ++it) {
        const int vidx = htid + (it << 8);
        const int kx = vidx >> 5;
        const int c4 = vidx & 31;
        const f4s val = *(const f4s*)(anchor + (c4 << 2));
        *(f4s*)(op + kx * ROWLEN + (NCH + 3) + (c4 << 2)) = val;
      }
      // xyz part: 24 rows x 3 floats
      if (htid < NK * 3) {
        const int kx = htid / 3;
        const int r = htid - kx * 3;
        const int si = s_idx2[h][kx];
        op[kx * ROWLEN + NCH + r] = xb[si * 3 + r];
      }
    }
    __syncthreads();   // protect s_idx2/s_aidx before next iteration
  }
}

extern "C" void kernel_launch(void* const* d_in, const int* in_sizes, int n_in,
                              void* d_out, int out_size, void* d_ws, size_t ws_size,
                              hipStream_t stream) {
  const float* xyz = (const float*)d_in[0];
  const float* points = (const float*)d_in[1];
  float* out = (float*)d_out;
  int* fps_idx = (int*)d_ws;                                    // 8*2048 ints (64 KB)
  u64* slots = (u64*)((char*)d_ws + (size_t)NBATCH * NGROUP * sizeof(int));  // 512 B

  // poison fps_idx (-1 sentinel) AND slots (tag 2047 garbage: provably never
  // false-matches — parity slots are rewritten at s=1,2 long before s=2047)
  hipMemsetAsync(d_ws, 0xFF,
                 (size_t)NBATCH * NGROUP * sizeof(int) +
                 (size_t)NBATCH * 2 * FPS_KS * sizeof(u64), stream);
  fused_kernel<<<dim3(FPS_BLKS + GBLOCKS), dim3(FPS_T), 0, stream>>>(
      xyz, points, fps_idx, slots, out);
}